// Round 6
// baseline (380.331 us; speedup 1.0000x reference)
//
#include <hip/hip_runtime.h>
#include <hip/hip_bf16.h>
#include <math.h>

#define H 120
#define W 216
#define C 256
#define NPIX (H*W)
#define PATCH 13
#define PP 169
#define RAD 6
#define TOPKN 36
#define OBJ 11
#define MD 4
#define CW 344   // padded corr row stride (338 -> 344)

typedef unsigned short ushort;
typedef unsigned int   uint;
typedef __attribute__((ext_vector_type(8))) __bf16 bf16x8;
typedef __attribute__((ext_vector_type(4))) float   f32x4;

#define PLANE_B ((size_t)NPIX * 512)   // bytes per hi/lo plane of a transposed tensor

__device__ inline ushort f2bf_rne(float x) {
  uint u = __float_as_uint(x);
  uint r = (u + 0x7FFFu + ((u >> 16) & 1u)) >> 16;
  return (ushort)r;
}
__device__ inline float bf2f(ushort h) { return __uint_as_float(((uint)h) << 16); }

// ---------------- kernel 0: transpose + hi/lo bf16 split ----------------
// grid (405 pix-chunks, 4 c-quarters, 3 tensors), block 256.
// out layout per tensor: [2 planes][NPIX][256] bf16 (hi plane then lo plane).
__global__ __launch_bounds__(256) void k_prep(const float* __restrict__ fq,
                      const float* __restrict__ fm0, const float* __restrict__ fm1,
                      char* fqt, char* fm0t, char* fm1t) {
  const float* src = (blockIdx.z == 0) ? fq : (blockIdx.z == 1) ? fm0 : fm1;
  char* dst = (blockIdx.z == 0) ? fqt : (blockIdx.z == 1) ? fm0t : fm1t;

  const int p0 = blockIdx.x * 64;
  const int c0 = blockIdx.y * 64;
  const int tid = threadIdx.x;

  __shared__ float ts[64 * 65];
  {
    int p = tid & 63, cl = tid >> 6;
    #pragma unroll
    for (int jj = 0; jj < 16; ++jj) {
      int c = 4 * jj + cl;
      ts[c * 65 + p] = src[(size_t)(c0 + c) * NPIX + p0 + p];
    }
  }
  __syncthreads();
  {
    int pl = tid >> 2, sub = tid & 3;
    ushort hb[16], lb[16];
    #pragma unroll
    for (int i = 0; i < 16; ++i) {
      float x = ts[(sub * 16 + i) * 65 + pl];
      ushort h = f2bf_rne(x);
      hb[i] = h;
      lb[i] = f2bf_rne(x - bf2f(h));
    }
    size_t off = (size_t)(p0 + pl) * 512 + (size_t)c0 * 2 + sub * 32;
    *(uint4*)(dst + off)            = ((uint4*)hb)[0];
    *(uint4*)(dst + off + 16)       = ((uint4*)hb)[1];
    *(uint4*)(dst + PLANE_B + off)      = ((uint4*)lb)[0];
    *(uint4*)(dst + PLANE_B + off + 16) = ((uint4*)lb)[1];
  }
}

// ---------------- kernel 1: mask downsample (::4,::4) ----------------
__global__ void k_downsample(const float* __restrict__ m0, const float* __restrict__ m1,
                             float* __restrict__ mds) {
  int i = blockIdx.x * 256 + threadIdx.x;
  const int total = 2 * OBJ * NPIX;
  if (i >= total) return;
  int fo = i / NPIX;
  int pix = i - fo * NPIX;
  int f = fo / OBJ, o = fo - f * OBJ;
  int y = pix / W, x = pix - y * W;
  const float* src = f ? m1 : m0;
  mds[i] = src[(size_t)o * (H*MD) * (W*MD) + (size_t)(MD*y) * (W*MD) + MD*x];
}

// ---------------- kernel 2 (MFMA, LDS-free): wave = (y, f, 16-x tile), all 13 di ----------------
// acc[13][2] f32x4 in VGPRs; A (fq row tile, 8 K-chunks, hi+lo) resident in 64 VGPRs;
// B streamed global(L2)->reg with immediate kc*64 offsets. Invalid-u columns are computed
// with clamped (garbage) B and zeroed at the store (exact: MFMA columns are independent).
// Per-acc K-chain identical to R5 (kc 0..7 x [AhBh, AhBl, AlBh]) -> corr bit-identical.
__global__ __launch_bounds__(256, 2) void k_corr_mfma(const char* __restrict__ fqt,
                        const char* __restrict__ fm0t, const char* __restrict__ fm1t,
                        float* __restrict__ corr) {
  int b = blockIdx.x;
  // XCD swizzle: 960 = 8 * 120; consecutive lb -> same y neighborhood on one XCD.
  int lb = (b & 7) * 120 + (b >> 3);
  int y   = lb >> 3;
  int rem = lb & 7;
  int f   = rem >> 2;
  int q   = rem & 2 ? 2 + (rem & 1) : (rem & 1);   // q in 0..3
  const int wv   = threadIdx.x >> 6;
  const int t    = q * 4 + wv;          // x-tile id, 0..15
  if (t >= 14) return;                  // 2 idle waves in q=3 blocks
  const int lane = threadIdx.x & 63;
  const int l15  = lane & 15, l4 = lane >> 4;

  const char* frame = f ? fm1t : fm0t;

  // ---- A fragments (resident): x = 16t + l15, octet l4, all 8 K-chunks, hi+lo ----
  int xA = 16 * t + l15;
  const char* pa = fqt + (size_t)(y * W + (xA < W ? xA : 0)) * 512 + l4 * 16;
  bf16x8 Ah[8], Al[8];
  #pragma unroll
  for (int kc = 0; kc < 8; ++kc) {
    Ah[kc] = *(const bf16x8*)(pa + kc * 64);
    Al[kc] = *(const bf16x8*)(pa + PLANE_B + kc * 64);
  }

  // ---- B column info for the two 16-groups: u = 16*(t+nt) + l15 - 8 ----
  int u0 = 16 * t + l15 - 8;
  int u1 = u0 + 16;
  bool uok0 = (u0 >= 0) && (u0 < W);
  bool uok1 = (u1 >= 0) && (u1 < W);
  size_t ub0 = (size_t)(uok0 ? u0 : 0) * 512 + (size_t)(l4 * 16);
  size_t ub1 = (size_t)(uok1 ? u1 : 0) * 512 + (size_t)(l4 * 16);

  f32x4 acc[13][2];
  #pragma unroll
  for (int di = 0; di < 13; ++di) {
    acc[di][0] = (f32x4){0.f, 0.f, 0.f, 0.f};
    acc[di][1] = (f32x4){0.f, 0.f, 0.f, 0.f};
  }

  #pragma unroll
  for (int di = 0; di < 13; ++di) {
    int rr = y + di - RAD;
    if (rr >= 0 && rr < H) {
      const char* rowb = frame + (size_t)rr * (W * 512);
      const char* p0 = rowb + ub0;
      const char* p1 = rowb + ub1;
      #pragma unroll
      for (int kc = 0; kc < 8; ++kc) {
        bf16x8 Bh0 = *(const bf16x8*)(p0 + kc * 64);
        bf16x8 Bl0 = *(const bf16x8*)(p0 + PLANE_B + kc * 64);
        bf16x8 Bh1 = *(const bf16x8*)(p1 + kc * 64);
        bf16x8 Bl1 = *(const bf16x8*)(p1 + PLANE_B + kc * 64);
        acc[di][0] = __builtin_amdgcn_mfma_f32_16x16x32_bf16(Ah[kc], Bh0, acc[di][0], 0, 0, 0);
        acc[di][0] = __builtin_amdgcn_mfma_f32_16x16x32_bf16(Ah[kc], Bl0, acc[di][0], 0, 0, 0);
        acc[di][0] = __builtin_amdgcn_mfma_f32_16x16x32_bf16(Al[kc], Bh0, acc[di][0], 0, 0, 0);
        acc[di][1] = __builtin_amdgcn_mfma_f32_16x16x32_bf16(Ah[kc], Bh1, acc[di][1], 0, 0, 0);
        acc[di][1] = __builtin_amdgcn_mfma_f32_16x16x32_bf16(Ah[kc], Bl1, acc[di][1], 0, 0, 0);
        acc[di][1] = __builtin_amdgcn_mfma_f32_16x16x32_bf16(Al[kc], Bh1, acc[di][1], 0, 0, 0);
      }
    }
  }

  // ---- band extraction: D[m][n] -> corr[x][f*PP + di*13 + dj], dj = 16nt + l15 - m - 2 ----
  float* cb = corr + (size_t)(y * W) * CW + f * PP;
  #pragma unroll
  for (int di = 0; di < 13; ++di) {
    #pragma unroll
    for (int nt = 0; nt < 2; ++nt) {
      bool uok = nt ? uok1 : uok0;   // store-time zeroing of invalid-u columns
      #pragma unroll
      for (int j = 0; j < 4; ++j) {
        int m  = l4 * 4 + j;
        int x  = 16 * t + m;
        int dj = 16 * nt + l15 - m - 2;
        if (x < W && dj >= 0 && dj < PATCH)
          cb[(size_t)x * CW + di * PATCH + dj] = uok ? acc[di][nt][j] * 0.0625f : 0.f;
      }
    }
  }
}

// ---------------- kernel 2 fallback (VALU, R2-validated) ----------------
__global__ __launch_bounds__(64) void k_corr_valu(const float* __restrict__ fq,
                       const float* __restrict__ fm0, const float* __restrict__ fm1,
                       float* __restrict__ corr) {
  int b = blockIdx.x;
  int lb = (b & 7) * 390 + (b >> 3);
  int y   = lb / 26;
  int r26 = lb - y * 26;
  int f   = r26 / 13;
  int di  = r26 - f * 13;
  const int tid = threadIdx.x;
  const int xg  = tid;
  const int r   = y + di - RAD;

  float* corr_base = corr + (size_t)(y * W) * CW + (f * PP + di * PATCH);

  if (r < 0 || r >= H) {
    if (xg < 54) {
      float* cp = corr_base + (size_t)(4 * xg) * CW;
      #pragma unroll
      for (int sub = 0; sub < 4; ++sub) {
        #pragma unroll
        for (int dj = 0; dj < PATCH; ++dj) cp[(size_t)sub * CW + dj] = 0.f;
      }
    }
    return;
  }

  const float* fm = f ? fm1 : fm0;
  __shared__ float fm_s[4 * 232];

  const float* pf[4];
  int  ldsoff[4];
  bool sval[4], mval[4];
  #pragma unroll
  for (int s = 0; s < 4; ++s) {
    int i = tid + 64 * s;
    sval[s] = (i < 232);
    int ii = sval[s] ? i : 0;
    int ch = ii / 58;
    int m  = ii - ch * 58;
    int x  = 4 * m - 8;
    mval[s] = sval[s] && (m >= 2) && (m <= 55);
    ldsoff[s] = ch * 232 + 4 * m;
    pf[s] = fm + (size_t)ch * NPIX + (size_t)r * W + (mval[s] ? x : 0);
  }

  const float* pq = fq + (size_t)y * W + 4 * ((xg < 54) ? xg : 0);

  float4 acc[PATCH];
  #pragma unroll
  for (int d = 0; d < PATCH; ++d) acc[d] = make_float4(0.f, 0.f, 0.f, 0.f);

  for (int c0 = 0; c0 < C; c0 += 4) {
    #pragma unroll
    for (int s = 0; s < 4; ++s) {
      if (sval[s]) {
        float4 v = make_float4(0.f, 0.f, 0.f, 0.f);
        if (mval[s]) v = *(const float4*)(pf[s]);
        *(float4*)&fm_s[ldsoff[s]] = v;
        pf[s] += 4 * (size_t)NPIX;
      }
    }
    __syncthreads();
    if (xg < 54) {
      #pragma unroll
      for (int ch = 0; ch < 4; ++ch) {
        float4 q4 = *(const float4*)(pq + (size_t)ch * NPIX);
        float rv[20];
        #pragma unroll
        for (int qq = 0; qq < 5; ++qq) {
          float4 t4 = *(const float4*)&fm_s[ch * 232 + 4 * xg + 4 * qq];
          rv[4*qq+0] = t4.x; rv[4*qq+1] = t4.y; rv[4*qq+2] = t4.z; rv[4*qq+3] = t4.w;
        }
        #pragma unroll
        for (int dj = 0; dj < PATCH; ++dj) {
          acc[dj].x += q4.x * rv[dj + 2];
          acc[dj].y += q4.y * rv[dj + 3];
          acc[dj].z += q4.z * rv[dj + 4];
          acc[dj].w += q4.w * rv[dj + 5];
        }
      }
      pq += 4 * (size_t)NPIX;
    }
    __syncthreads();
  }

  if (xg < 54) {
    float* cp = corr_base + (size_t)(4 * xg) * CW;
    #pragma unroll
    for (int dj = 0; dj < PATCH; ++dj) {
      cp[dj]                  = acc[dj].x * 0.0625f;
      cp[(size_t)1 * CW + dj] = acc[dj].y * 0.0625f;
      cp[(size_t)2 * CW + dj] = acc[dj].z * 0.0625f;
      cp[(size_t)3 * CW + dj] = acc[dj].w * 0.0625f;
    }
  }
}

// ---------------- kernel 3: per-pixel top-36 + softmax + mask gather (validated) ----------------
__global__ __launch_bounds__(256) void k_topk(const float* __restrict__ corr,
                       const float* __restrict__ mds, float* __restrict__ out) {
  int wid = (blockIdx.x * 256 + threadIdx.x) >> 6;
  int lane = threadIdx.x & 63;
  if (wid >= NPIX) return;
  const float* cr = corr + (size_t)wid * CW;

  float v[6];
  #pragma unroll
  for (int s = 0; s < 6; ++s) {
    int idx = lane + 64 * s;
    v[s] = (idx < 2 * PP) ? cr[idx] : -INFINITY;
  }

  float m = 0.f, sum = 0.f, my_w = 0.f;
  int my_idx = 0;
  for (int k = 0; k < TOPKN; ++k) {
    float bv = v[0]; int bs = 0;
    #pragma unroll
    for (int qq = 1; qq < 6; ++qq) { if (v[qq] > bv) { bv = v[qq]; bs = qq; } }
    int bidx = lane + 64 * bs;
    #pragma unroll
    for (int off = 32; off >= 1; off >>= 1) {
      float ov = __shfl_xor(bv, off, 64);
      int   oi = __shfl_xor(bidx, off, 64);
      if (ov > bv || (ov == bv && oi < bidx)) { bv = ov; bidx = oi; }
    }
    if (k == 0) m = bv;
    float wv = __expf(bv - m);
    sum += wv;
    if (lane == k) { my_w = wv; my_idx = bidx; }
    if ((bidx & 63) == lane) {
      int s = bidx >> 6;
      #pragma unroll
      for (int qq = 0; qq < 6; ++qq) { if (s == qq) v[qq] = -INFINITY; }
    }
  }

  int y = wid / W, x = wid - (wid / W) * W;
  float part[OBJ];
  #pragma unroll
  for (int o = 0; o < OBJ; ++o) part[o] = 0.f;
  if (lane < TOPKN) {
    int idx = my_idx;
    int f = (idx >= PP) ? 1 : 0;
    int rr = idx - f * PP;
    int di = rr / PATCH, dj = rr - (rr / PATCH) * PATCH;
    int yy = y + di - RAD, xx = x + dj - RAD;
    if (yy >= 0 && yy < H && xx >= 0 && xx < W) {
      const float* mb = mds + ((size_t)f * OBJ) * NPIX + yy * W + xx;
      #pragma unroll
      for (int o = 0; o < OBJ; ++o) part[o] = my_w * mb[(size_t)o * NPIX];
    }
  }
  float inv = 1.f / sum;
  #pragma unroll
  for (int o = 0; o < OBJ; ++o) {
    float p = part[o];
    #pragma unroll
    for (int off = 32; off >= 1; off >>= 1) p += __shfl_xor(p, off, 64);
    if (lane == 0) out[(size_t)o * NPIX + wid] = p * inv;
  }
}

extern "C" void kernel_launch(void* const* d_in, const int* in_sizes, int n_in,
                              void* d_out, int out_size, void* d_ws, size_t ws_size,
                              hipStream_t stream) {
  const float* fq  = (const float*)d_in[0];
  const float* fm0 = (const float*)d_in[1];
  const float* fm1 = (const float*)d_in[2];
  const float* m0  = (const float*)d_in[3];
  const float* m1  = (const float*)d_in[4];
  float* out = (float*)d_out;

  char* ws = (char*)d_ws;
  size_t off = 0;
  auto alloc = [&](size_t sz) { size_t o = off; off = (off + sz + 1023) & ~(size_t)1023; return o; };

  size_t mds_o  = alloc((size_t)2 * OBJ * NPIX * sizeof(float));
  size_t corr_o = alloc((size_t)NPIX * CW * sizeof(float));
  size_t fqt_o  = alloc(2 * PLANE_B);
  size_t fm0t_o = alloc(2 * PLANE_B);
  size_t fm1t_o = alloc(2 * PLANE_B);
  size_t needed = off;

  float* mds  = (float*)(ws + mds_o);
  float* corr = (float*)(ws + corr_o);

  k_downsample<<<(2 * OBJ * NPIX + 255) / 256, 256, 0, stream>>>(m0, m1, mds);

  if (ws_size >= needed) {
    char* fqt  = ws + fqt_o;
    char* fm0t = ws + fm0t_o;
    char* fm1t = ws + fm1t_o;
    dim3 gp(405, 4, 3);
    k_prep<<<gp, 256, 0, stream>>>(fq, fm0, fm1, fqt, fm0t, fm1t);
    k_corr_mfma<<<960, 256, 0, stream>>>(fqt, fm0t, fm1t, corr);
  } else {
    k_corr_valu<<<120 * 26, 64, 0, stream>>>(fq, fm0, fm1, corr);
  }

  k_topk<<<NPIX / 4, 256, 0, stream>>>(corr, mds, out);
}

// Round 7
// 245.055 us; speedup vs baseline: 1.5520x; 1.5520x over previous
//
#include <hip/hip_runtime.h>
#include <hip/hip_bf16.h>
#include <math.h>

#define H 120
#define W 216
#define C 256
#define NPIX (H*W)
#define PATCH 13
#define PP 169
#define RAD 6
#define TOPKN 36
#define OBJ 11
#define MD 4
#define CW 344   // padded corr row stride (338 -> 344)

typedef unsigned short ushort;
typedef unsigned int   uint;
typedef __attribute__((ext_vector_type(8))) __bf16 bf16x8;
typedef __attribute__((ext_vector_type(4))) float   f32x4;

#define PLANE_B ((size_t)NPIX * 512)   // bytes per hi/lo plane of a transposed tensor

// corr tile geometry
#define YT 8                    // y rows per block
#define RT 20                   // staged fm rows = YT + 12
#define XT 16                   // x cols per block (one M tile)
#define UW 32                   // u window = XT + 16
#define PXS 144                 // staged px stride: 2 planes x 64B + 16B pad (bank-uniform)
#define ROWS (UW * PXS)         // 4608 B per staged row
#define NXT 14                  // ceil(216/16)
#define NYT 15                  // 120/8
#define NWG (NXT * 2 * NYT)     // 420 blocks

__device__ inline ushort f2bf_rne(float x) {
  uint u = __float_as_uint(x);
  uint r = (u + 0x7FFFu + ((u >> 16) & 1u)) >> 16;
  return (ushort)r;
}
__device__ inline float bf2f(ushort h) { return __uint_as_float(((uint)h) << 16); }

// ---------------- kernel 0: transpose + hi/lo bf16 split ----------------
__global__ __launch_bounds__(256) void k_prep(const float* __restrict__ fq,
                      const float* __restrict__ fm0, const float* __restrict__ fm1,
                      char* fqt, char* fm0t, char* fm1t) {
  const float* src = (blockIdx.z == 0) ? fq : (blockIdx.z == 1) ? fm0 : fm1;
  char* dst = (blockIdx.z == 0) ? fqt : (blockIdx.z == 1) ? fm0t : fm1t;

  const int p0 = blockIdx.x * 64;
  const int c0 = blockIdx.y * 64;
  const int tid = threadIdx.x;

  __shared__ float ts[64 * 65];
  {
    int p = tid & 63, cl = tid >> 6;
    #pragma unroll
    for (int jj = 0; jj < 16; ++jj) {
      int c = 4 * jj + cl;
      ts[c * 65 + p] = src[(size_t)(c0 + c) * NPIX + p0 + p];
    }
  }
  __syncthreads();
  {
    int pl = tid >> 2, sub = tid & 3;
    ushort hb[16], lb[16];
    #pragma unroll
    for (int i = 0; i < 16; ++i) {
      float x = ts[(sub * 16 + i) * 65 + pl];
      ushort h = f2bf_rne(x);
      hb[i] = h;
      lb[i] = f2bf_rne(x - bf2f(h));
    }
    size_t off = (size_t)(p0 + pl) * 512 + (size_t)c0 * 2 + sub * 32;
    *(uint4*)(dst + off)            = ((uint4*)hb)[0];
    *(uint4*)(dst + off + 16)       = ((uint4*)hb)[1];
    *(uint4*)(dst + PLANE_B + off)      = ((uint4*)lb)[0];
    *(uint4*)(dst + PLANE_B + off + 16) = ((uint4*)lb)[1];
  }
}

// ---------------- kernel 1: mask downsample (::4,::4) ----------------
__global__ void k_downsample(const float* __restrict__ m0, const float* __restrict__ m1,
                             float* __restrict__ mds) {
  int i = blockIdx.x * 256 + threadIdx.x;
  const int total = 2 * OBJ * NPIX;
  if (i >= total) return;
  int fo = i / NPIX;
  int pix = i - fo * NPIX;
  int f = fo / OBJ, o = fo - f * OBJ;
  int y = pix / W, x = pix - y * W;
  const float* src = f ? m1 : m0;
  mds[i] = src[(size_t)o * (H*MD) * (W*MD) + (size_t)(MD*y) * (W*MD) + MD*x];
}

// ---------------- kernel 2 (MFMA + LDS B-reuse): block = (x16, y8, f), wave = one y ----------------
// B for the whole tile (20 fm rows x 32 u-px, hi+lo) staged per K32-chunk into LDS and
// consumed by all 8 waves x 13 di  -> ~5x less L3 traffic than R6's register streaming.
// Per-acc K-chain (kc 0..7 x [AhBh, AhBl, AlBh]) identical to R6 -> corr bit-identical.
__global__ __launch_bounds__(512, 2) void k_corr_mfma(const char* __restrict__ fqt,
                        const char* __restrict__ fm0t, const char* __restrict__ fm1t,
                        float* __restrict__ corr) {
  // bijective XCD swizzle (m204), nwg = 420 = 8*52 + 4: consecutive wgid = adjacent y-tiles
  int b = blockIdx.x;
  int xcd = b & 7;
  int wgid = ((xcd < 4) ? xcd * 53 : 4 * 53 + (xcd - 4) * 52) + (b >> 3);
  int yt   = wgid % NYT;
  int rest = wgid / NYT;
  int f    = rest & 1;
  int xt   = rest >> 1;

  const int y0 = yt * YT;
  const int X0 = xt * XT;
  const int tid  = threadIdx.x;
  const int wy   = tid >> 6;           // wave id = y offset in tile
  const int lane = tid & 63;
  const int l15  = lane & 15, l4 = lane >> 4;
  const int y    = y0 + wy;

  const char* frame = f ? fm1t : fm0t;

  __shared__ __align__(16) char bsm[RT * ROWS];   // 92160 B

  // ---- staging descriptors: 5120 granules of 16B = 512 threads x 10 ----
  // granule g: ri = g>>8; px = (g&255)>>3; p = (g>>2)&1; q = g&3
  uint soff[10], ldso[10];
  #pragma unroll
  for (int s = 0; s < 10; ++s) {
    int g  = tid + 512 * s;
    int ri = g >> 8;
    int rem = g & 255;
    int px = rem >> 3;
    int p  = (rem >> 2) & 1;
    int q  = rem & 3;
    int r  = y0 - 6 + ri;  r = (r < 0) ? 0 : (r >= H ? H - 1 : r);     // clamp (garbage rows never consumed)
    int u  = X0 - 8 + px;  u = (u < 0) ? 0 : (u >= W ? W - 1 : u);     // clamp (garbage cols zeroed at store)
    ldso[s] = ri * ROWS + px * PXS + p * 64 + q * 16;
    soff[s] = (uint)(p * PLANE_B + (size_t)(r * W + u) * 512 + q * 16);
  }

  // ---- A fragments (resident): x = X0 + l15, octet l4, all 8 K-chunks, hi+lo ----
  {
  }
  int xA = X0 + l15;
  const char* pa = fqt + (size_t)(y * W + (xA < W ? xA : W - 1)) * 512 + l4 * 16;
  bf16x8 Ah[8], Al[8];
  #pragma unroll
  for (int kc = 0; kc < 8; ++kc) {
    Ah[kc] = *(const bf16x8*)(pa + kc * 64);
    Al[kc] = *(const bf16x8*)(pa + PLANE_B + kc * 64);
  }

  // B read base offsets (within a staged row): n-col = 16*nt + l15, quarter l4
  const uint boff0 = (uint)((0 * 16 + l15) * PXS + l4 * 16);
  const uint boff1 = (uint)((1 * 16 + l15) * PXS + l4 * 16);

  // column validity (store-time zeroing, proven in R6)
  int u0 = X0 + l15 - 8;
  int u1 = u0 + 16;
  bool uok0 = (u0 >= 0) && (u0 < W);
  bool uok1 = (u1 >= 0) && (u1 < W);

  f32x4 acc[13][2];
  #pragma unroll
  for (int di = 0; di < 13; ++di) {
    acc[di][0] = (f32x4){0.f, 0.f, 0.f, 0.f};
    acc[di][1] = (f32x4){0.f, 0.f, 0.f, 0.f};
  }

  for (int kc = 0; kc < 8; ++kc) {
    // ---- stage B chunk: 20 rows x 32 px x (hi|lo) x 64B ----
    #pragma unroll
    for (int s = 0; s < 10; ++s)
      *(uint4*)(bsm + ldso[s]) = *(const uint4*)(frame + (size_t)soff[s] + kc * 64);
    __syncthreads();

    #pragma unroll
    for (int di = 0; di < 13; ++di) {
      int rr = y + di - RAD;              // wave-uniform branch
      if (rr >= 0 && rr < H) {
        const char* rb = bsm + (wy + di) * ROWS;
        {
          const char* pb = rb + boff0;
          bf16x8 Bhv = *(const bf16x8*)(pb);
          bf16x8 Blv = *(const bf16x8*)(pb + 64);
          acc[di][0] = __builtin_amdgcn_mfma_f32_16x16x32_bf16(Ah[kc], Bhv, acc[di][0], 0, 0, 0);
          acc[di][0] = __builtin_amdgcn_mfma_f32_16x16x32_bf16(Ah[kc], Blv, acc[di][0], 0, 0, 0);
          acc[di][0] = __builtin_amdgcn_mfma_f32_16x16x32_bf16(Al[kc], Bhv, acc[di][0], 0, 0, 0);
        }
        {
          const char* pb = rb + boff1;
          bf16x8 Bhv = *(const bf16x8*)(pb);
          bf16x8 Blv = *(const bf16x8*)(pb + 64);
          acc[di][1] = __builtin_amdgcn_mfma_f32_16x16x32_bf16(Ah[kc], Bhv, acc[di][1], 0, 0, 0);
          acc[di][1] = __builtin_amdgcn_mfma_f32_16x16x32_bf16(Ah[kc], Blv, acc[di][1], 0, 0, 0);
          acc[di][1] = __builtin_amdgcn_mfma_f32_16x16x32_bf16(Al[kc], Bhv, acc[di][1], 0, 0, 0);
        }
      }
    }
    __syncthreads();
  }

  // ---- band extraction: D[m][n] -> corr[x][f*PP + di*13 + dj], dj = 16nt + l15 - m - 2 ----
  float* cb = corr + (size_t)(y * W) * CW + f * PP;
  #pragma unroll
  for (int di = 0; di < 13; ++di) {
    #pragma unroll
    for (int nt = 0; nt < 2; ++nt) {
      bool uok = nt ? uok1 : uok0;
      #pragma unroll
      for (int j = 0; j < 4; ++j) {
        int m  = l4 * 4 + j;
        int x  = X0 + m;
        int dj = 16 * nt + l15 - m - 2;
        if (x < W && dj >= 0 && dj < PATCH)
          cb[(size_t)x * CW + di * PATCH + dj] = uok ? acc[di][nt][j] * 0.0625f : 0.f;
      }
    }
  }
}

// ---------------- kernel 2 fallback (VALU, R2-validated) ----------------
__global__ __launch_bounds__(64) void k_corr_valu(const float* __restrict__ fq,
                       const float* __restrict__ fm0, const float* __restrict__ fm1,
                       float* __restrict__ corr) {
  int b = blockIdx.x;
  int lb = (b & 7) * 390 + (b >> 3);
  int y   = lb / 26;
  int r26 = lb - y * 26;
  int f   = r26 / 13;
  int di  = r26 - f * 13;
  const int tid = threadIdx.x;
  const int xg  = tid;
  const int r   = y + di - RAD;

  float* corr_base = corr + (size_t)(y * W) * CW + (f * PP + di * PATCH);

  if (r < 0 || r >= H) {
    if (xg < 54) {
      float* cp = corr_base + (size_t)(4 * xg) * CW;
      #pragma unroll
      for (int sub = 0; sub < 4; ++sub) {
        #pragma unroll
        for (int dj = 0; dj < PATCH; ++dj) cp[(size_t)sub * CW + dj] = 0.f;
      }
    }
    return;
  }

  const float* fm = f ? fm1 : fm0;
  __shared__ float fm_s[4 * 232];

  const float* pf[4];
  int  ldsoff[4];
  bool sval[4], mval[4];
  #pragma unroll
  for (int s = 0; s < 4; ++s) {
    int i = tid + 64 * s;
    sval[s] = (i < 232);
    int ii = sval[s] ? i : 0;
    int ch = ii / 58;
    int m  = ii - ch * 58;
    int x  = 4 * m - 8;
    mval[s] = sval[s] && (m >= 2) && (m <= 55);
    ldsoff[s] = ch * 232 + 4 * m;
    pf[s] = fm + (size_t)ch * NPIX + (size_t)r * W + (mval[s] ? x : 0);
  }

  const float* pq = fq + (size_t)y * W + 4 * ((xg < 54) ? xg : 0);

  float4 acc[PATCH];
  #pragma unroll
  for (int d = 0; d < PATCH; ++d) acc[d] = make_float4(0.f, 0.f, 0.f, 0.f);

  for (int c0 = 0; c0 < C; c0 += 4) {
    #pragma unroll
    for (int s = 0; s < 4; ++s) {
      if (sval[s]) {
        float4 v = make_float4(0.f, 0.f, 0.f, 0.f);
        if (mval[s]) v = *(const float4*)(pf[s]);
        *(float4*)&fm_s[ldsoff[s]] = v;
        pf[s] += 4 * (size_t)NPIX;
      }
    }
    __syncthreads();
    if (xg < 54) {
      #pragma unroll
      for (int ch = 0; ch < 4; ++ch) {
        float4 q4 = *(const float4*)(pq + (size_t)ch * NPIX);
        float rv[20];
        #pragma unroll
        for (int qq = 0; qq < 5; ++qq) {
          float4 t4 = *(const float4*)&fm_s[ch * 232 + 4 * xg + 4 * qq];
          rv[4*qq+0] = t4.x; rv[4*qq+1] = t4.y; rv[4*qq+2] = t4.z; rv[4*qq+3] = t4.w;
        }
        #pragma unroll
        for (int dj = 0; dj < PATCH; ++dj) {
          acc[dj].x += q4.x * rv[dj + 2];
          acc[dj].y += q4.y * rv[dj + 3];
          acc[dj].z += q4.z * rv[dj + 4];
          acc[dj].w += q4.w * rv[dj + 5];
        }
      }
      pq += 4 * (size_t)NPIX;
    }
    __syncthreads();
  }

  if (xg < 54) {
    float* cp = corr_base + (size_t)(4 * xg) * CW;
    #pragma unroll
    for (int dj = 0; dj < PATCH; ++dj) {
      cp[dj]                  = acc[dj].x * 0.0625f;
      cp[(size_t)1 * CW + dj] = acc[dj].y * 0.0625f;
      cp[(size_t)2 * CW + dj] = acc[dj].z * 0.0625f;
      cp[(size_t)3 * CW + dj] = acc[dj].w * 0.0625f;
    }
  }
}

// ---------------- kernel 3: per-pixel top-36 + softmax + mask gather (validated) ----------------
__global__ __launch_bounds__(256) void k_topk(const float* __restrict__ corr,
                       const float* __restrict__ mds, float* __restrict__ out) {
  int wid = (blockIdx.x * 256 + threadIdx.x) >> 6;
  int lane = threadIdx.x & 63;
  if (wid >= NPIX) return;
  const float* cr = corr + (size_t)wid * CW;

  float v[6];
  #pragma unroll
  for (int s = 0; s < 6; ++s) {
    int idx = lane + 64 * s;
    v[s] = (idx < 2 * PP) ? cr[idx] : -INFINITY;
  }

  float m = 0.f, sum = 0.f, my_w = 0.f;
  int my_idx = 0;
  for (int k = 0; k < TOPKN; ++k) {
    float bv = v[0]; int bs = 0;
    #pragma unroll
    for (int qq = 1; qq < 6; ++qq) { if (v[qq] > bv) { bv = v[qq]; bs = qq; } }
    int bidx = lane + 64 * bs;
    #pragma unroll
    for (int off = 32; off >= 1; off >>= 1) {
      float ov = __shfl_xor(bv, off, 64);
      int   oi = __shfl_xor(bidx, off, 64);
      if (ov > bv || (ov == bv && oi < bidx)) { bv = ov; bidx = oi; }
    }
    if (k == 0) m = bv;
    float wv = __expf(bv - m);
    sum += wv;
    if (lane == k) { my_w = wv; my_idx = bidx; }
    if ((bidx & 63) == lane) {
      int s = bidx >> 6;
      #pragma unroll
      for (int qq = 0; qq < 6; ++qq) { if (s == qq) v[qq] = -INFINITY; }
    }
  }

  int y = wid / W, x = wid - (wid / W) * W;
  float part[OBJ];
  #pragma unroll
  for (int o = 0; o < OBJ; ++o) part[o] = 0.f;
  if (lane < TOPKN) {
    int idx = my_idx;
    int f = (idx >= PP) ? 1 : 0;
    int rr = idx - f * PP;
    int di = rr / PATCH, dj = rr - (rr / PATCH) * PATCH;
    int yy = y + di - RAD, xx = x + dj - RAD;
    if (yy >= 0 && yy < H && xx >= 0 && xx < W) {
      const float* mb = mds + ((size_t)f * OBJ) * NPIX + yy * W + xx;
      #pragma unroll
      for (int o = 0; o < OBJ; ++o) part[o] = my_w * mb[(size_t)o * NPIX];
    }
  }
  float inv = 1.f / sum;
  #pragma unroll
  for (int o = 0; o < OBJ; ++o) {
    float p = part[o];
    #pragma unroll
    for (int off = 32; off >= 1; off >>= 1) p += __shfl_xor(p, off, 64);
    if (lane == 0) out[(size_t)o * NPIX + wid] = p * inv;
  }
}

extern "C" void kernel_launch(void* const* d_in, const int* in_sizes, int n_in,
                              void* d_out, int out_size, void* d_ws, size_t ws_size,
                              hipStream_t stream) {
  const float* fq  = (const float*)d_in[0];
  const float* fm0 = (const float*)d_in[1];
  const float* fm1 = (const float*)d_in[2];
  const float* m0  = (const float*)d_in[3];
  const float* m1  = (const float*)d_in[4];
  float* out = (float*)d_out;

  char* ws = (char*)d_ws;
  size_t off = 0;
  auto alloc = [&](size_t sz) { size_t o = off; off = (off + sz + 1023) & ~(size_t)1023; return o; };

  size_t mds_o  = alloc((size_t)2 * OBJ * NPIX * sizeof(float));
  size_t corr_o = alloc((size_t)NPIX * CW * sizeof(float));
  size_t fqt_o  = alloc(2 * PLANE_B);
  size_t fm0t_o = alloc(2 * PLANE_B);
  size_t fm1t_o = alloc(2 * PLANE_B);
  size_t needed = off;

  float* mds  = (float*)(ws + mds_o);
  float* corr = (float*)(ws + corr_o);

  k_downsample<<<(2 * OBJ * NPIX + 255) / 256, 256, 0, stream>>>(m0, m1, mds);

  if (ws_size >= needed) {
    char* fqt  = ws + fqt_o;
    char* fm0t = ws + fm0t_o;
    char* fm1t = ws + fm1t_o;
    dim3 gp(405, 4, 3);
    k_prep<<<gp, 256, 0, stream>>>(fq, fm0, fm1, fqt, fm0t, fm1t);
    k_corr_mfma<<<NWG, 512, 0, stream>>>(fqt, fm0t, fm1t, corr);
  } else {
    k_corr_valu<<<120 * 26, 64, 0, stream>>>(fq, fm0, fm1, corr);
  }

  k_topk<<<NPIX / 4, 256, 0, stream>>>(corr, mds, out);
}

// Round 8
// 144.309 us; speedup vs baseline: 2.6355x; 1.6981x over previous
//
#include <hip/hip_runtime.h>
#include <hip/hip_bf16.h>
#include <math.h>

#define H 120
#define W 216
#define C 256
#define NPIX (H*W)
#define PATCH 13
#define PP 169
#define RAD 6
#define TOPKN 36
#define OBJ 11
#define MD 4
#define CW 344   // padded corr row stride (338 -> 344)

typedef unsigned short ushort;
typedef unsigned int   uint;
typedef __attribute__((ext_vector_type(8))) __bf16 bf16x8;
typedef __attribute__((ext_vector_type(4))) float   f32x4;

#define PLANE_B ((size_t)NPIX * 512)   // bytes per hi/lo plane of a transposed tensor

// corr tile geometry
#define YT 8                    // y rows per block
#define RT 20                   // staged fm rows = YT + 12
#define XT 16                   // x cols per block (one M tile)
#define UW 32                   // u window = XT + 16
#define PXS 144                 // staged px stride: 2 planes x 64B + 16B pad (bank-uniform)
#define ROWS (UW * PXS)         // 4608 B per staged row
#define NXT 14                  // ceil(216/16)
#define NYT 15                  // 120/8
#define NWG (NXT * 2 * NYT)     // 420 blocks

__device__ inline ushort f2bf_rne(float x) {
  uint u = __float_as_uint(x);
  uint r = (u + 0x7FFFu + ((u >> 16) & 1u)) >> 16;
  return (ushort)r;
}
__device__ inline float bf2f(ushort h) { return __uint_as_float(((uint)h) << 16); }

// ---------------- kernel 0: transpose + hi/lo bf16 split ----------------
__global__ __launch_bounds__(256) void k_prep(const float* __restrict__ fq,
                      const float* __restrict__ fm0, const float* __restrict__ fm1,
                      char* fqt, char* fm0t, char* fm1t) {
  const float* src = (blockIdx.z == 0) ? fq : (blockIdx.z == 1) ? fm0 : fm1;
  char* dst = (blockIdx.z == 0) ? fqt : (blockIdx.z == 1) ? fm0t : fm1t;

  const int p0 = blockIdx.x * 64;
  const int c0 = blockIdx.y * 64;
  const int tid = threadIdx.x;

  __shared__ float ts[64 * 65];
  {
    int p = tid & 63, cl = tid >> 6;
    #pragma unroll
    for (int jj = 0; jj < 16; ++jj) {
      int c = 4 * jj + cl;
      ts[c * 65 + p] = src[(size_t)(c0 + c) * NPIX + p0 + p];
    }
  }
  __syncthreads();
  {
    int pl = tid >> 2, sub = tid & 3;
    ushort hb[16], lb[16];
    #pragma unroll
    for (int i = 0; i < 16; ++i) {
      float x = ts[(sub * 16 + i) * 65 + pl];
      ushort h = f2bf_rne(x);
      hb[i] = h;
      lb[i] = f2bf_rne(x - bf2f(h));
    }
    size_t off = (size_t)(p0 + pl) * 512 + (size_t)c0 * 2 + sub * 32;
    *(uint4*)(dst + off)            = ((uint4*)hb)[0];
    *(uint4*)(dst + off + 16)       = ((uint4*)hb)[1];
    *(uint4*)(dst + PLANE_B + off)      = ((uint4*)lb)[0];
    *(uint4*)(dst + PLANE_B + off + 16) = ((uint4*)lb)[1];
  }
}

// ---------------- kernel 1: mask downsample (::4,::4) ----------------
__global__ void k_downsample(const float* __restrict__ m0, const float* __restrict__ m1,
                             float* __restrict__ mds) {
  int i = blockIdx.x * 256 + threadIdx.x;
  const int total = 2 * OBJ * NPIX;
  if (i >= total) return;
  int fo = i / NPIX;
  int pix = i - fo * NPIX;
  int f = fo / OBJ, o = fo - f * OBJ;
  int y = pix / W, x = pix - y * W;
  const float* src = f ? m1 : m0;
  mds[i] = src[(size_t)o * (H*MD) * (W*MD) + (size_t)(MD*y) * (W*MD) + MD*x];
}

// ---------------- kernel 2 (MFMA + LDS B-reuse): block = (x16, y8, f), wave = one y ----------------
// (R7-validated; untouched)
__global__ __launch_bounds__(512, 2) void k_corr_mfma(const char* __restrict__ fqt,
                        const char* __restrict__ fm0t, const char* __restrict__ fm1t,
                        float* __restrict__ corr) {
  int b = blockIdx.x;
  int xcd = b & 7;
  int wgid = ((xcd < 4) ? xcd * 53 : 4 * 53 + (xcd - 4) * 52) + (b >> 3);
  int yt   = wgid % NYT;
  int rest = wgid / NYT;
  int f    = rest & 1;
  int xt   = rest >> 1;

  const int y0 = yt * YT;
  const int X0 = xt * XT;
  const int tid  = threadIdx.x;
  const int wy   = tid >> 6;
  const int lane = tid & 63;
  const int l15  = lane & 15, l4 = lane >> 4;
  const int y    = y0 + wy;

  const char* frame = f ? fm1t : fm0t;

  __shared__ __align__(16) char bsm[RT * ROWS];   // 92160 B

  uint soff[10], ldso[10];
  #pragma unroll
  for (int s = 0; s < 10; ++s) {
    int g  = tid + 512 * s;
    int ri = g >> 8;
    int rem = g & 255;
    int px = rem >> 3;
    int p  = (rem >> 2) & 1;
    int q  = rem & 3;
    int r  = y0 - 6 + ri;  r = (r < 0) ? 0 : (r >= H ? H - 1 : r);
    int u  = X0 - 8 + px;  u = (u < 0) ? 0 : (u >= W ? W - 1 : u);
    ldso[s] = ri * ROWS + px * PXS + p * 64 + q * 16;
    soff[s] = (uint)(p * PLANE_B + (size_t)(r * W + u) * 512 + q * 16);
  }

  int xA = X0 + l15;
  const char* pa = fqt + (size_t)(y * W + (xA < W ? xA : W - 1)) * 512 + l4 * 16;
  bf16x8 Ah[8], Al[8];
  #pragma unroll
  for (int kc = 0; kc < 8; ++kc) {
    Ah[kc] = *(const bf16x8*)(pa + kc * 64);
    Al[kc] = *(const bf16x8*)(pa + PLANE_B + kc * 64);
  }

  const uint boff0 = (uint)((0 * 16 + l15) * PXS + l4 * 16);
  const uint boff1 = (uint)((1 * 16 + l15) * PXS + l4 * 16);

  int u0 = X0 + l15 - 8;
  int u1 = u0 + 16;
  bool uok0 = (u0 >= 0) && (u0 < W);
  bool uok1 = (u1 >= 0) && (u1 < W);

  f32x4 acc[13][2];
  #pragma unroll
  for (int di = 0; di < 13; ++di) {
    acc[di][0] = (f32x4){0.f, 0.f, 0.f, 0.f};
    acc[di][1] = (f32x4){0.f, 0.f, 0.f, 0.f};
  }

  for (int kc = 0; kc < 8; ++kc) {
    #pragma unroll
    for (int s = 0; s < 10; ++s)
      *(uint4*)(bsm + ldso[s]) = *(const uint4*)(frame + (size_t)soff[s] + kc * 64);
    __syncthreads();

    #pragma unroll
    for (int di = 0; di < 13; ++di) {
      int rr = y + di - RAD;
      if (rr >= 0 && rr < H) {
        const char* rb = bsm + (wy + di) * ROWS;
        {
          const char* pb = rb + boff0;
          bf16x8 Bhv = *(const bf16x8*)(pb);
          bf16x8 Blv = *(const bf16x8*)(pb + 64);
          acc[di][0] = __builtin_amdgcn_mfma_f32_16x16x32_bf16(Ah[kc], Bhv, acc[di][0], 0, 0, 0);
          acc[di][0] = __builtin_amdgcn_mfma_f32_16x16x32_bf16(Ah[kc], Blv, acc[di][0], 0, 0, 0);
          acc[di][0] = __builtin_amdgcn_mfma_f32_16x16x32_bf16(Al[kc], Bhv, acc[di][0], 0, 0, 0);
        }
        {
          const char* pb = rb + boff1;
          bf16x8 Bhv = *(const bf16x8*)(pb);
          bf16x8 Blv = *(const bf16x8*)(pb + 64);
          acc[di][1] = __builtin_amdgcn_mfma_f32_16x16x32_bf16(Ah[kc], Bhv, acc[di][1], 0, 0, 0);
          acc[di][1] = __builtin_amdgcn_mfma_f32_16x16x32_bf16(Ah[kc], Blv, acc[di][1], 0, 0, 0);
          acc[di][1] = __builtin_amdgcn_mfma_f32_16x16x32_bf16(Al[kc], Bhv, acc[di][1], 0, 0, 0);
        }
      }
    }
    __syncthreads();
  }

  float* cb = corr + (size_t)(y * W) * CW + f * PP;
  #pragma unroll
  for (int di = 0; di < 13; ++di) {
    #pragma unroll
    for (int nt = 0; nt < 2; ++nt) {
      bool uok = nt ? uok1 : uok0;
      #pragma unroll
      for (int j = 0; j < 4; ++j) {
        int m  = l4 * 4 + j;
        int x  = X0 + m;
        int dj = 16 * nt + l15 - m - 2;
        if (x < W && dj >= 0 && dj < PATCH)
          cb[(size_t)x * CW + di * PATCH + dj] = uok ? acc[di][nt][j] * 0.0625f : 0.f;
      }
    }
  }
}

// ---------------- kernel 2 fallback (VALU, R2-validated) ----------------
__global__ __launch_bounds__(64) void k_corr_valu(const float* __restrict__ fq,
                       const float* __restrict__ fm0, const float* __restrict__ fm1,
                       float* __restrict__ corr) {
  int b = blockIdx.x;
  int lb = (b & 7) * 390 + (b >> 3);
  int y   = lb / 26;
  int r26 = lb - y * 26;
  int f   = r26 / 13;
  int di  = r26 - f * 13;
  const int tid = threadIdx.x;
  const int xg  = tid;
  const int r   = y + di - RAD;

  float* corr_base = corr + (size_t)(y * W) * CW + (f * PP + di * PATCH);

  if (r < 0 || r >= H) {
    if (xg < 54) {
      float* cp = corr_base + (size_t)(4 * xg) * CW;
      #pragma unroll
      for (int sub = 0; sub < 4; ++sub) {
        #pragma unroll
        for (int dj = 0; dj < PATCH; ++dj) cp[(size_t)sub * CW + dj] = 0.f;
      }
    }
    return;
  }

  const float* fm = f ? fm1 : fm0;
  __shared__ float fm_s[4 * 232];

  const float* pf[4];
  int  ldsoff[4];
  bool sval[4], mval[4];
  #pragma unroll
  for (int s = 0; s < 4; ++s) {
    int i = tid + 64 * s;
    sval[s] = (i < 232);
    int ii = sval[s] ? i : 0;
    int ch = ii / 58;
    int m  = ii - ch * 58;
    int x  = 4 * m - 8;
    mval[s] = sval[s] && (m >= 2) && (m <= 55);
    ldsoff[s] = ch * 232 + 4 * m;
    pf[s] = fm + (size_t)ch * NPIX + (size_t)r * W + (mval[s] ? x : 0);
  }

  const float* pq = fq + (size_t)y * W + 4 * ((xg < 54) ? xg : 0);

  float4 acc[PATCH];
  #pragma unroll
  for (int d = 0; d < PATCH; ++d) acc[d] = make_float4(0.f, 0.f, 0.f, 0.f);

  for (int c0 = 0; c0 < C; c0 += 4) {
    #pragma unroll
    for (int s = 0; s < 4; ++s) {
      if (sval[s]) {
        float4 v = make_float4(0.f, 0.f, 0.f, 0.f);
        if (mval[s]) v = *(const float4*)(pf[s]);
        *(float4*)&fm_s[ldsoff[s]] = v;
        pf[s] += 4 * (size_t)NPIX;
      }
    }
    __syncthreads();
    if (xg < 54) {
      #pragma unroll
      for (int ch = 0; ch < 4; ++ch) {
        float4 q4 = *(const float4*)(pq + (size_t)ch * NPIX);
        float rv[20];
        #pragma unroll
        for (int qq = 0; qq < 5; ++qq) {
          float4 t4 = *(const float4*)&fm_s[ch * 232 + 4 * xg + 4 * qq];
          rv[4*qq+0] = t4.x; rv[4*qq+1] = t4.y; rv[4*qq+2] = t4.z; rv[4*qq+3] = t4.w;
        }
        #pragma unroll
        for (int dj = 0; dj < PATCH; ++dj) {
          acc[dj].x += q4.x * rv[dj + 2];
          acc[dj].y += q4.y * rv[dj + 3];
          acc[dj].z += q4.z * rv[dj + 4];
          acc[dj].w += q4.w * rv[dj + 5];
        }
      }
      pq += 4 * (size_t)NPIX;
    }
    __syncthreads();
  }

  if (xg < 54) {
    float* cp = corr_base + (size_t)(4 * xg) * CW;
    #pragma unroll
    for (int dj = 0; dj < PATCH; ++dj) {
      cp[dj]                  = acc[dj].x * 0.0625f;
      cp[(size_t)1 * CW + dj] = acc[dj].y * 0.0625f;
      cp[(size_t)2 * CW + dj] = acc[dj].z * 0.0625f;
      cp[(size_t)3 * CW + dj] = acc[dj].w * 0.0625f;
    }
  }
}

// ---------------- kernel 3: per-pixel top-36 via ballot-count rank select ----------------
// one wave per pixel. Exact selection: x0 = min{x : #(mono(v) > x) <= 35} by 32-step
// binary search (6 v_cmp + scalar popcount per probe); ties at x0 broken by lowest
// global index via mbcnt prefix (matches jax.lax.top_k). Softmax uses exp(v - t):
// ratio-identical to exp(v - max).
__global__ __launch_bounds__(256) void k_topk(const float* __restrict__ corr,
                       const float* __restrict__ mds, float* __restrict__ out) {
  int wid = (blockIdx.x * 256 + threadIdx.x) >> 6;
  int lane = threadIdx.x & 63;
  if (wid >= NPIX) return;
  const float* cr = corr + (size_t)wid * CW;

  float v[6]; uint ui[6];
  #pragma unroll
  for (int s = 0; s < 6; ++s) {
    int idx = lane + 64 * s;
    bool ok = idx < 2 * PP;
    float f = ok ? cr[idx] : 0.f;
    v[s] = f;
    uint bb = __float_as_uint(f);
    uint u = bb ^ (uint)(((int)bb >> 31) | 0x80000000);
    ui[s] = ok ? u : 0u;     // padding strictly below all real values
  }

  // ---- binary search for x0 = min{x : count(ui > x) <= 35} ----
  uint blo = 0u, bhi = 0xFFFFFFFFu;
  for (int it = 0; it < 32; ++it) {
    uint mid = blo + ((bhi - blo) >> 1);
    int c = 0;
    #pragma unroll
    for (int s = 0; s < 6; ++s)
      c += __popcll(__ballot(ui[s] > mid));
    if (c <= 35) bhi = mid; else blo = mid + 1;
  }
  const uint x0 = blo;

  int c_gt = 0;
  #pragma unroll
  for (int s = 0; s < 6; ++s) c_gt += __popcll(__ballot(ui[s] > x0));
  const int need = 36 - c_gt;        // >= 1 tied slots to accept (lowest index first)

  // threshold back to float (wave-uniform)
  uint tb = (x0 & 0x80000000u) ? (x0 ^ 0x80000000u) : ~x0;
  const float tf = __uint_as_float(tb);

  // ---- accept + weights ----
  float w[6];
  float zp = 0.f;
  int prior = 0;
  #pragma unroll
  for (int s = 0; s < 6; ++s) {
    unsigned long long tie = __ballot(ui[s] == x0);
    uint below = __builtin_amdgcn_mbcnt_hi((uint)(tie >> 32),
                  __builtin_amdgcn_mbcnt_lo((uint)tie, 0u));
    bool acc = (ui[s] > x0) || ((ui[s] == x0) && ((prior + (int)below) < need));
    prior += __popcll(tie);
    w[s] = acc ? __expf(v[s] - tf) : 0.f;   // accepted => v >= tf => w >= 1
    zp += w[s];
  }
  float Z = zp;
  #pragma unroll
  for (int off = 32; off >= 1; off >>= 1) Z += __shfl_xor(Z, off, 64);

  // ---- gather masks for accepted slots ----
  int y = wid / W, x = wid - (wid / W) * W;
  float no[OBJ];
  #pragma unroll
  for (int o = 0; o < OBJ; ++o) no[o] = 0.f;
  #pragma unroll
  for (int s = 0; s < 6; ++s) {
    if (w[s] > 0.f) {
      int idx = lane + 64 * s;
      int ff = idx >= PP;
      int r = idx - ff * PP;
      int di = r / PATCH, dj = r - (r / PATCH) * PATCH;
      int yy = y + di - RAD, xx = x + dj - RAD;
      if (yy >= 0 && yy < H && xx >= 0 && xx < W) {
        const float* mb = mds + ((size_t)ff * OBJ) * NPIX + yy * W + xx;
        #pragma unroll
        for (int o = 0; o < OBJ; ++o) no[o] += w[s] * mb[(size_t)o * NPIX];
      }
    }
  }
  float inv = 1.f / Z;
  #pragma unroll
  for (int o = 0; o < OBJ; ++o) {
    float p = no[o];
    #pragma unroll
    for (int off = 32; off >= 1; off >>= 1) p += __shfl_xor(p, off, 64);
    if (lane == 0) out[(size_t)o * NPIX + wid] = p * inv;
  }
}

extern "C" void kernel_launch(void* const* d_in, const int* in_sizes, int n_in,
                              void* d_out, int out_size, void* d_ws, size_t ws_size,
                              hipStream_t stream) {
  const float* fq  = (const float*)d_in[0];
  const float* fm0 = (const float*)d_in[1];
  const float* fm1 = (const float*)d_in[2];
  const float* m0  = (const float*)d_in[3];
  const float* m1  = (const float*)d_in[4];
  float* out = (float*)d_out;

  char* ws = (char*)d_ws;
  size_t off = 0;
  auto alloc = [&](size_t sz) { size_t o = off; off = (off + sz + 1023) & ~(size_t)1023; return o; };

  size_t mds_o  = alloc((size_t)2 * OBJ * NPIX * sizeof(float));
  size_t corr_o = alloc((size_t)NPIX * CW * sizeof(float));
  size_t fqt_o  = alloc(2 * PLANE_B);
  size_t fm0t_o = alloc(2 * PLANE_B);
  size_t fm1t_o = alloc(2 * PLANE_B);
  size_t needed = off;

  float* mds  = (float*)(ws + mds_o);
  float* corr = (float*)(ws + corr_o);

  k_downsample<<<(2 * OBJ * NPIX + 255) / 256, 256, 0, stream>>>(m0, m1, mds);

  if (ws_size >= needed) {
    char* fqt  = ws + fqt_o;
    char* fm0t = ws + fm0t_o;
    char* fm1t = ws + fm1t_o;
    dim3 gp(405, 4, 3);
    k_prep<<<gp, 256, 0, stream>>>(fq, fm0, fm1, fqt, fm0t, fm1t);
    k_corr_mfma<<<NWG, 512, 0, stream>>>(fqt, fm0t, fm1t, corr);
  } else {
    k_corr_valu<<<120 * 26, 64, 0, stream>>>(fq, fm0, fm1, corr);
  }

  k_topk<<<NPIX / 4, 256, 0, stream>>>(corr, mds, out);
}

// Round 9
// 141.856 us; speedup vs baseline: 2.6811x; 1.0173x over previous
//
#include <hip/hip_runtime.h>
#include <hip/hip_bf16.h>
#include <math.h>

#define H 120
#define W 216
#define C 256
#define NPIX (H*W)
#define PATCH 13
#define PP 169
#define RAD 6
#define TOPKN 36
#define OBJ 11
#define MD 4
#define CW 344   // padded corr row stride (338 -> 344)

typedef unsigned short ushort;
typedef unsigned int   uint;
typedef __attribute__((ext_vector_type(8))) __bf16 bf16x8;
typedef __attribute__((ext_vector_type(4))) float   f32x4;

#define PLANE_B ((size_t)NPIX * 512)   // bytes per hi/lo plane of a transposed tensor

// corr tile geometry
#define YT 8                    // y rows per block
#define RT 20                   // staged fm rows = YT + 12
#define XT 16                   // x cols per block (one M tile)
#define UW 32                   // u window = XT + 16
#define PXS 128                 // staged px stride: 2 planes x 64B, XOR-swizzled (no pad)
#define ROWS (UW * PXS)         // 4096 B per staged row
#define NXT 14                  // ceil(216/16)
#define NYT 15                  // 120/8
#define NWG (NXT * 2 * NYT)     // 420 blocks

__device__ inline ushort f2bf_rne(float x) {
  uint u = __float_as_uint(x);
  uint r = (u + 0x7FFFu + ((u >> 16) & 1u)) >> 16;
  return (ushort)r;
}
__device__ inline float bf2f(ushort h) { return __uint_as_float(((uint)h) << 16); }

// ---------------- kernel 0: transpose + hi/lo bf16 split ----------------
__global__ __launch_bounds__(256) void k_prep(const float* __restrict__ fq,
                      const float* __restrict__ fm0, const float* __restrict__ fm1,
                      char* fqt, char* fm0t, char* fm1t) {
  const float* src = (blockIdx.z == 0) ? fq : (blockIdx.z == 1) ? fm0 : fm1;
  char* dst = (blockIdx.z == 0) ? fqt : (blockIdx.z == 1) ? fm0t : fm1t;

  const int p0 = blockIdx.x * 64;
  const int c0 = blockIdx.y * 64;
  const int tid = threadIdx.x;

  __shared__ float ts[64 * 65];
  {
    int p = tid & 63, cl = tid >> 6;
    #pragma unroll
    for (int jj = 0; jj < 16; ++jj) {
      int c = 4 * jj + cl;
      ts[c * 65 + p] = src[(size_t)(c0 + c) * NPIX + p0 + p];
    }
  }
  __syncthreads();
  {
    int pl = tid >> 2, sub = tid & 3;
    ushort hb[16], lb[16];
    #pragma unroll
    for (int i = 0; i < 16; ++i) {
      float x = ts[(sub * 16 + i) * 65 + pl];
      ushort h = f2bf_rne(x);
      hb[i] = h;
      lb[i] = f2bf_rne(x - bf2f(h));
    }
    size_t off = (size_t)(p0 + pl) * 512 + (size_t)c0 * 2 + sub * 32;
    *(uint4*)(dst + off)            = ((uint4*)hb)[0];
    *(uint4*)(dst + off + 16)       = ((uint4*)hb)[1];
    *(uint4*)(dst + PLANE_B + off)      = ((uint4*)lb)[0];
    *(uint4*)(dst + PLANE_B + off + 16) = ((uint4*)lb)[1];
  }
}

// ---------------- kernel 1: mask downsample (::4,::4) ----------------
__global__ void k_downsample(const float* __restrict__ m0, const float* __restrict__ m1,
                             float* __restrict__ mds) {
  int i = blockIdx.x * 256 + threadIdx.x;
  const int total = 2 * OBJ * NPIX;
  if (i >= total) return;
  int fo = i / NPIX;
  int pix = i - fo * NPIX;
  int f = fo / OBJ, o = fo - f * OBJ;
  int y = pix / W, x = pix - y * W;
  const float* src = f ? m1 : m0;
  mds[i] = src[(size_t)o * (H*MD) * (W*MD) + (size_t)(MD*y) * (W*MD) + MD*x];
}

// ---------------- kernel 2 (MFMA + LDS B-reuse, 80 KiB -> 2 blocks/CU) ----------------
// block = (x16, y8, f), wave = one y. B staged per K32-chunk into XOR-swizzled LDS
// (addr ^= (px&7)<<4, identical at write and read; bijective per 128-B px slot).
// K-chain (kc 0..7 x [AhBh, AhBl, AlBh]) identical to R8 -> corr bit-identical.
__global__ __launch_bounds__(512, 2) void k_corr_mfma(const char* __restrict__ fqt,
                        const char* __restrict__ fm0t, const char* __restrict__ fm1t,
                        float* __restrict__ corr) {
  int b = blockIdx.x;
  int xcd = b & 7;
  int wgid = ((xcd < 4) ? xcd * 53 : 4 * 53 + (xcd - 4) * 52) + (b >> 3);
  int yt   = wgid % NYT;
  int rest = wgid / NYT;
  int f    = rest & 1;
  int xt   = rest >> 1;

  const int y0 = yt * YT;
  const int X0 = xt * XT;
  const int tid  = threadIdx.x;
  const int wy   = tid >> 6;
  const int lane = tid & 63;
  const int l15  = lane & 15, l4 = lane >> 4;
  const int y    = y0 + wy;

  const char* frame = f ? fm1t : fm0t;

  __shared__ __align__(16) char bsm[RT * ROWS];   // 81920 B = 80 KiB -> 2 blocks/CU

  // ---- staging descriptors: 5120 granules of 16B = 512 threads x 10 ----
  // granule g: ri = g>>8; px = (g&255)>>3; p = (g>>2)&1; q = g&3
  uint soff[10], ldso[10];
  #pragma unroll
  for (int s = 0; s < 10; ++s) {
    int g  = tid + 512 * s;
    int ri = g >> 8;
    int rem = g & 255;
    int px = rem >> 3;
    int p  = (rem >> 2) & 1;
    int q  = rem & 3;
    int r  = y0 - 6 + ri;  r = (r < 0) ? 0 : (r >= H ? H - 1 : r);
    int u  = X0 - 8 + px;  u = (u < 0) ? 0 : (u >= W ? W - 1 : u);
    ldso[s] = (uint)((ri * ROWS + px * PXS + p * 64 + q * 16) ^ ((px & 7) << 4));
    soff[s] = (uint)(p * PLANE_B + (size_t)(r * W + u) * 512 + q * 16);
  }

  // ---- A fragments (resident): x = X0 + l15, octet l4, all 8 K-chunks, hi+lo ----
  int xA = X0 + l15;
  const char* pa = fqt + (size_t)(y * W + (xA < W ? xA : W - 1)) * 512 + l4 * 16;
  bf16x8 Ah[8], Al[8];
  #pragma unroll
  for (int kc = 0; kc < 8; ++kc) {
    Ah[kc] = *(const bf16x8*)(pa + kc * 64);
    Al[kc] = *(const bf16x8*)(pa + PLANE_B + kc * 64);
  }

  // B read offsets (within a staged row), swizzled identically to the writes
  const int px0 = l15, px1 = 16 + l15;
  const uint sw  = (uint)((l15 & 7) << 4);   // (px0&7)==(px1&7)==(l15&7)
  const uint b0h = (uint)((px0 * PXS +      l4 * 16) ^ sw);
  const uint b0l = (uint)((px0 * PXS + 64 + l4 * 16) ^ sw);
  const uint b1h = (uint)((px1 * PXS +      l4 * 16) ^ sw);
  const uint b1l = (uint)((px1 * PXS + 64 + l4 * 16) ^ sw);

  int u0 = X0 + l15 - 8;
  int u1 = u0 + 16;
  bool uok0 = (u0 >= 0) && (u0 < W);
  bool uok1 = (u1 >= 0) && (u1 < W);

  f32x4 acc[13][2];
  #pragma unroll
  for (int di = 0; di < 13; ++di) {
    acc[di][0] = (f32x4){0.f, 0.f, 0.f, 0.f};
    acc[di][1] = (f32x4){0.f, 0.f, 0.f, 0.f};
  }

  for (int kc = 0; kc < 8; ++kc) {
    #pragma unroll
    for (int s = 0; s < 10; ++s)
      *(uint4*)(bsm + ldso[s]) = *(const uint4*)(frame + (size_t)soff[s] + kc * 64);
    __syncthreads();

    #pragma unroll
    for (int di = 0; di < 13; ++di) {
      int rr = y + di - RAD;
      if (rr >= 0 && rr < H) {
        const char* rb = bsm + (wy + di) * ROWS;
        {
          bf16x8 Bhv = *(const bf16x8*)(rb + b0h);
          bf16x8 Blv = *(const bf16x8*)(rb + b0l);
          acc[di][0] = __builtin_amdgcn_mfma_f32_16x16x32_bf16(Ah[kc], Bhv, acc[di][0], 0, 0, 0);
          acc[di][0] = __builtin_amdgcn_mfma_f32_16x16x32_bf16(Ah[kc], Blv, acc[di][0], 0, 0, 0);
          acc[di][0] = __builtin_amdgcn_mfma_f32_16x16x32_bf16(Al[kc], Bhv, acc[di][0], 0, 0, 0);
        }
        {
          bf16x8 Bhv = *(const bf16x8*)(rb + b1h);
          bf16x8 Blv = *(const bf16x8*)(rb + b1l);
          acc[di][1] = __builtin_amdgcn_mfma_f32_16x16x32_bf16(Ah[kc], Bhv, acc[di][1], 0, 0, 0);
          acc[di][1] = __builtin_amdgcn_mfma_f32_16x16x32_bf16(Ah[kc], Blv, acc[di][1], 0, 0, 0);
          acc[di][1] = __builtin_amdgcn_mfma_f32_16x16x32_bf16(Al[kc], Bhv, acc[di][1], 0, 0, 0);
        }
      }
    }
    __syncthreads();
  }

  float* cb = corr + (size_t)(y * W) * CW + f * PP;
  #pragma unroll
  for (int di = 0; di < 13; ++di) {
    #pragma unroll
    for (int nt = 0; nt < 2; ++nt) {
      bool uok = nt ? uok1 : uok0;
      #pragma unroll
      for (int j = 0; j < 4; ++j) {
        int m  = l4 * 4 + j;
        int x  = X0 + m;
        int dj = 16 * nt + l15 - m - 2;
        if (x < W && dj >= 0 && dj < PATCH)
          cb[(size_t)x * CW + di * PATCH + dj] = uok ? acc[di][nt][j] * 0.0625f : 0.f;
      }
    }
  }
}

// ---------------- kernel 2 fallback (VALU, R2-validated) ----------------
__global__ __launch_bounds__(64) void k_corr_valu(const float* __restrict__ fq,
                       const float* __restrict__ fm0, const float* __restrict__ fm1,
                       float* __restrict__ corr) {
  int b = blockIdx.x;
  int lb = (b & 7) * 390 + (b >> 3);
  int y   = lb / 26;
  int r26 = lb - y * 26;
  int f   = r26 / 13;
  int di  = r26 - f * 13;
  const int tid = threadIdx.x;
  const int xg  = tid;
  const int r   = y + di - RAD;

  float* corr_base = corr + (size_t)(y * W) * CW + (f * PP + di * PATCH);

  if (r < 0 || r >= H) {
    if (xg < 54) {
      float* cp = corr_base + (size_t)(4 * xg) * CW;
      #pragma unroll
      for (int sub = 0; sub < 4; ++sub) {
        #pragma unroll
        for (int dj = 0; dj < PATCH; ++dj) cp[(size_t)sub * CW + dj] = 0.f;
      }
    }
    return;
  }

  const float* fm = f ? fm1 : fm0;
  __shared__ float fm_s[4 * 232];

  const float* pf[4];
  int  ldsoff[4];
  bool sval[4], mval[4];
  #pragma unroll
  for (int s = 0; s < 4; ++s) {
    int i = tid + 64 * s;
    sval[s] = (i < 232);
    int ii = sval[s] ? i : 0;
    int ch = ii / 58;
    int m  = ii - ch * 58;
    int x  = 4 * m - 8;
    mval[s] = sval[s] && (m >= 2) && (m <= 55);
    ldsoff[s] = ch * 232 + 4 * m;
    pf[s] = fm + (size_t)ch * NPIX + (size_t)r * W + (mval[s] ? x : 0);
  }

  const float* pq = fq + (size_t)y * W + 4 * ((xg < 54) ? xg : 0);

  float4 acc[PATCH];
  #pragma unroll
  for (int d = 0; d < PATCH; ++d) acc[d] = make_float4(0.f, 0.f, 0.f, 0.f);

  for (int c0 = 0; c0 < C; c0 += 4) {
    #pragma unroll
    for (int s = 0; s < 4; ++s) {
      if (sval[s]) {
        float4 v = make_float4(0.f, 0.f, 0.f, 0.f);
        if (mval[s]) v = *(const float4*)(pf[s]);
        *(float4*)&fm_s[ldsoff[s]] = v;
        pf[s] += 4 * (size_t)NPIX;
      }
    }
    __syncthreads();
    if (xg < 54) {
      #pragma unroll
      for (int ch = 0; ch < 4; ++ch) {
        float4 q4 = *(const float4*)(pq + (size_t)ch * NPIX);
        float rv[20];
        #pragma unroll
        for (int qq = 0; qq < 5; ++qq) {
          float4 t4 = *(const float4*)&fm_s[ch * 232 + 4 * xg + 4 * qq];
          rv[4*qq+0] = t4.x; rv[4*qq+1] = t4.y; rv[4*qq+2] = t4.z; rv[4*qq+3] = t4.w;
        }
        #pragma unroll
        for (int dj = 0; dj < PATCH; ++dj) {
          acc[dj].x += q4.x * rv[dj + 2];
          acc[dj].y += q4.y * rv[dj + 3];
          acc[dj].z += q4.z * rv[dj + 4];
          acc[dj].w += q4.w * rv[dj + 5];
        }
      }
      pq += 4 * (size_t)NPIX;
    }
    __syncthreads();
  }

  if (xg < 54) {
    float* cp = corr_base + (size_t)(4 * xg) * CW;
    #pragma unroll
    for (int dj = 0; dj < PATCH; ++dj) {
      cp[dj]                  = acc[dj].x * 0.0625f;
      cp[(size_t)1 * CW + dj] = acc[dj].y * 0.0625f;
      cp[(size_t)2 * CW + dj] = acc[dj].z * 0.0625f;
      cp[(size_t)3 * CW + dj] = acc[dj].w * 0.0625f;
    }
  }
}

// ---------------- kernel 3: per-pixel top-36 via ballot-count rank select (R8-validated) ----------------
__global__ __launch_bounds__(256) void k_topk(const float* __restrict__ corr,
                       const float* __restrict__ mds, float* __restrict__ out) {
  int wid = (blockIdx.x * 256 + threadIdx.x) >> 6;
  int lane = threadIdx.x & 63;
  if (wid >= NPIX) return;
  const float* cr = corr + (size_t)wid * CW;

  float v[6]; uint ui[6];
  #pragma unroll
  for (int s = 0; s < 6; ++s) {
    int idx = lane + 64 * s;
    bool ok = idx < 2 * PP;
    float f = ok ? cr[idx] : 0.f;
    v[s] = f;
    uint bb = __float_as_uint(f);
    uint u = bb ^ (uint)(((int)bb >> 31) | 0x80000000);
    ui[s] = ok ? u : 0u;
  }

  uint blo = 0u, bhi = 0xFFFFFFFFu;
  for (int it = 0; it < 32; ++it) {
    uint mid = blo + ((bhi - blo) >> 1);
    int c = 0;
    #pragma unroll
    for (int s = 0; s < 6; ++s)
      c += __popcll(__ballot(ui[s] > mid));
    if (c <= 35) bhi = mid; else blo = mid + 1;
  }
  const uint x0 = blo;

  int c_gt = 0;
  #pragma unroll
  for (int s = 0; s < 6; ++s) c_gt += __popcll(__ballot(ui[s] > x0));
  const int need = 36 - c_gt;

  uint tb = (x0 & 0x80000000u) ? (x0 ^ 0x80000000u) : ~x0;
  const float tf = __uint_as_float(tb);

  float w[6];
  float zp = 0.f;
  int prior = 0;
  #pragma unroll
  for (int s = 0; s < 6; ++s) {
    unsigned long long tie = __ballot(ui[s] == x0);
    uint below = __builtin_amdgcn_mbcnt_hi((uint)(tie >> 32),
                  __builtin_amdgcn_mbcnt_lo((uint)tie, 0u));
    bool acc = (ui[s] > x0) || ((ui[s] == x0) && ((prior + (int)below) < need));
    prior += __popcll(tie);
    w[s] = acc ? __expf(v[s] - tf) : 0.f;
    zp += w[s];
  }
  float Z = zp;
  #pragma unroll
  for (int off = 32; off >= 1; off >>= 1) Z += __shfl_xor(Z, off, 64);

  int y = wid / W, x = wid - (wid / W) * W;
  float no[OBJ];
  #pragma unroll
  for (int o = 0; o < OBJ; ++o) no[o] = 0.f;
  #pragma unroll
  for (int s = 0; s < 6; ++s) {
    if (w[s] > 0.f) {
      int idx = lane + 64 * s;
      int ff = idx >= PP;
      int r = idx - ff * PP;
      int di = r / PATCH, dj = r - (r / PATCH) * PATCH;
      int yy = y + di - RAD, xx = x + dj - RAD;
      if (yy >= 0 && yy < H && xx >= 0 && xx < W) {
        const float* mb = mds + ((size_t)ff * OBJ) * NPIX + yy * W + xx;
        #pragma unroll
        for (int o = 0; o < OBJ; ++o) no[o] += w[s] * mb[(size_t)o * NPIX];
      }
    }
  }
  float inv = 1.f / Z;
  #pragma unroll
  for (int o = 0; o < OBJ; ++o) {
    float p = no[o];
    #pragma unroll
    for (int off = 32; off >= 1; off >>= 1) p += __shfl_xor(p, off, 64);
    if (lane == 0) out[(size_t)o * NPIX + wid] = p * inv;
  }
}

extern "C" void kernel_launch(void* const* d_in, const int* in_sizes, int n_in,
                              void* d_out, int out_size, void* d_ws, size_t ws_size,
                              hipStream_t stream) {
  const float* fq  = (const float*)d_in[0];
  const float* fm0 = (const float*)d_in[1];
  const float* fm1 = (const float*)d_in[2];
  const float* m0  = (const float*)d_in[3];
  const float* m1  = (const float*)d_in[4];
  float* out = (float*)d_out;

  char* ws = (char*)d_ws;
  size_t off = 0;
  auto alloc = [&](size_t sz) { size_t o = off; off = (off + sz + 1023) & ~(size_t)1023; return o; };

  size_t mds_o  = alloc((size_t)2 * OBJ * NPIX * sizeof(float));
  size_t corr_o = alloc((size_t)NPIX * CW * sizeof(float));
  size_t fqt_o  = alloc(2 * PLANE_B);
  size_t fm0t_o = alloc(2 * PLANE_B);
  size_t fm1t_o = alloc(2 * PLANE_B);
  size_t needed = off;

  float* mds  = (float*)(ws + mds_o);
  float* corr = (float*)(ws + corr_o);

  k_downsample<<<(2 * OBJ * NPIX + 255) / 256, 256, 0, stream>>>(m0, m1, mds);

  if (ws_size >= needed) {
    char* fqt  = ws + fqt_o;
    char* fm0t = ws + fm0t_o;
    char* fm1t = ws + fm1t_o;
    dim3 gp(405, 4, 3);
    k_prep<<<gp, 256, 0, stream>>>(fq, fm0, fm1, fqt, fm0t, fm1t);
    k_corr_mfma<<<NWG, 512, 0, stream>>>(fqt, fm0t, fm1t, corr);
  } else {
    k_corr_valu<<<120 * 26, 64, 0, stream>>>(fq, fm0, fm1, corr);
  }

  k_topk<<<NPIX / 4, 256, 0, stream>>>(corr, mds, out);
}